// Round 1
// baseline (1041.162 us; speedup 1.0000x reference)
//
#include <hip/hip_runtime.h>
#include <hip/hip_bf16.h>

typedef __bf16 bf16x8 __attribute__((ext_vector_type(8)));
typedef float f32x4 __attribute__((ext_vector_type(4)));

__device__ __forceinline__ void gload16(const void* g, void* l) {
  __builtin_amdgcn_global_load_lds(
      (const __attribute__((address_space(1))) void*)g,
      (__attribute__((address_space(3))) void*)l, 16, 0, 0);
}

__device__ __forceinline__ unsigned short f2bf(float f) {
  __hip_bfloat16 h = __float2bfloat16(f);
  union { __hip_bfloat16 h; unsigned short u; } c;
  c.h = h;
  return c.u;
}

__device__ __forceinline__ void fwht16(float v[16]) {
#pragma unroll
  for (int s = 1; s < 16; s <<= 1) {
#pragma unroll
    for (int i = 0; i < 16; i++) {
      if ((i & s) == 0) {
        float a = v[i], b = v[i | s];
        v[i] = a + b;
        v[i | s] = a - b;
      }
    }
  }
}

// ---------------- FWHT #1: h1 = bf16( fwht(x*SU) / 2048 ) ----------------
// One block per row of 4096. 256 threads; FWHT_4096 = F16 (bits 8-11) x F16
// (bits 4-7) x F16 (bits 0-3): three register-level 16-pt transforms with two
// LDS transposes (pad-17 layout -> near-conflict-free).
__global__ __launch_bounds__(256) void fwht1_kernel(
    const float* __restrict__ x, const float* __restrict__ SU,
    unsigned short* __restrict__ H1) {
  __shared__ float lds[256 * 17];
  const int t = threadIdx.x;
  const size_t row = blockIdx.x;
  const float* xr = x + row * 4096;
  float v[16];
#pragma unroll
  for (int n2 = 0; n2 < 16; n2++) {
    int n = n2 * 256 + t;
    v[n2] = xr[n] * SU[n];
  }
  fwht16(v);  // over n2 -> j2
  const int n1 = t >> 4, n0 = t & 15;
#pragma unroll
  for (int j2 = 0; j2 < 16; j2++) lds[(j2 * 16 + n1) * 17 + n0] = v[j2];
  __syncthreads();
  // phase B: thread owns (j2 = t>>4, n0 = t&15), transforms over n1
#pragma unroll
  for (int k = 0; k < 16; k++) v[k] = lds[((t >> 4) * 16 + k) * 17 + (t & 15)];
  fwht16(v);  // n1 -> j1 (write back in place: slots are thread-private here)
#pragma unroll
  for (int k = 0; k < 16; k++) lds[((t >> 4) * 16 + k) * 17 + (t & 15)] = v[k];
  __syncthreads();
  // phase C: thread owns (j2,j1) = t, transforms over n0
#pragma unroll
  for (int k = 0; k < 16; k++) v[k] = lds[t * 17 + k];
  fwht16(v);  // n0 -> j0 ; thread holds out[t*16 + j0]
  const float cst = 1.0f / 2048.0f;  // (1/sqrt(4096)) / 32
  union { unsigned short u[16]; uint4 q[2]; } o;
#pragma unroll
  for (int k = 0; k < 16; k++) o.u[k] = f2bf(v[k] * cst);
  uint4* dst = (uint4*)(H1 + row * 4096 + (size_t)t * 16);
  dst[0] = o.q[0];
  dst[1] = o.q[1];
}

// ---------------- W conversion: Wb[m][n] = bf16(W[m][n] * Wscale[m]) -------
__global__ __launch_bounds__(256) void convw_kernel(
    const float4* __restrict__ W4, const float* __restrict__ Wscale,
    uint2* __restrict__ Wb4, int total4, int Nq) {
  int i = blockIdx.x * 256 + threadIdx.x;
  if (i >= total4) return;
  float4 w = W4[i];
  float s = Wscale[i / Nq];
  unsigned int lo = (unsigned)f2bf(w.x * s) | ((unsigned)f2bf(w.y * s) << 16);
  unsigned int hi = (unsigned)f2bf(w.z * s) | ((unsigned)f2bf(w.w * s) << 16);
  Wb4[i] = make_uint2(lo, hi);
}

// ---------------- GEMM: C[t][m] = sum_n H1[t][n] * Wb[m][n] ---------------
// m97 structure: 128x128 tile, BK=32, 4 waves (2x2, 64x64 each),
// global_load_lds width 16, 16x16x32 bf16 MFMA, fp32 out.
__global__ __launch_bounds__(256) void gemm_kernel(
    const unsigned short* __restrict__ A, const unsigned short* __restrict__ B,
    float* __restrict__ C, int T, int M, int K) {
  __shared__ unsigned short As[128 * 32];
  __shared__ unsigned short Bs[128 * 32];
  const int nbn = M >> 7;
  const int cpx = gridDim.x >> 3;  // gridDim.x divisible by 8
  int bid = blockIdx.x;
  bid = (bid & 7) * cpx + (bid >> 3);  // XCD-aware swizzle (bijective)
  const int brow = (bid / nbn) << 7;
  const int bcol = (bid % nbn) << 7;
  const int tid = threadIdx.x;
  const int lane = tid & 63;
  const int wid = tid >> 6;
  const int wr = (wid >> 1) * 64, wc = (wid & 1) * 64;
  const unsigned short* Ag = A + (size_t)brow * K;
  const unsigned short* Bg = B + (size_t)bcol * K;
  const int sr0 = tid >> 2;        // staging row (chunk 0)
  const int sc = (tid & 3) * 8;    // staging col
  f32x4 acc[4][4];
#pragma unroll
  for (int i = 0; i < 4; i++)
#pragma unroll
    for (int j = 0; j < 4; j++) acc[i][j] = (f32x4){0.f, 0.f, 0.f, 0.f};

  const int kq = (lane >> 4) * 8;  // k-offset of this lane's fragment
  const int fr = lane & 15;        // row within 16x16 fragment
  for (int kt = 0; kt < K; kt += 32) {
    gload16(Ag + (size_t)sr0 * K + kt + sc, &As[tid * 8]);
    gload16(Ag + (size_t)(sr0 + 64) * K + kt + sc, &As[2048 + tid * 8]);
    gload16(Bg + (size_t)sr0 * K + kt + sc, &Bs[tid * 8]);
    gload16(Bg + (size_t)(sr0 + 64) * K + kt + sc, &Bs[2048 + tid * 8]);
    __syncthreads();
    bf16x8 af[4], bfr[4];
#pragma unroll
    for (int i = 0; i < 4; i++)
      af[i] = *(const bf16x8*)&As[(wr + i * 16 + fr) * 32 + kq];
#pragma unroll
    for (int j = 0; j < 4; j++)
      bfr[j] = *(const bf16x8*)&Bs[(wc + j * 16 + fr) * 32 + kq];
#pragma unroll
    for (int i = 0; i < 4; i++)
#pragma unroll
      for (int j = 0; j < 4; j++)
        acc[i][j] = __builtin_amdgcn_mfma_f32_16x16x32_bf16(af[i], bfr[j],
                                                            acc[i][j], 0, 0, 0);
    __syncthreads();
  }
  // C/D layout: col = lane&15, row = (lane>>4)*4 + q  [m89-verified]
  const int crow0 = brow + wr + (lane >> 4) * 4;
  const int ccol0 = bcol + wc + fr;
#pragma unroll
  for (int i = 0; i < 4; i++)
#pragma unroll
    for (int j = 0; j < 4; j++)
#pragma unroll
      for (int q = 0; q < 4; q++)
        C[(size_t)(crow0 + i * 16 + q) * M + ccol0 + j * 16] = acc[i][j][q];
}

// ---------------- FWHT #2 (in-place on d_out): out = fwht(Y)*0.5*SV ------
__global__ __launch_bounds__(256) void fwht2_kernel(
    float* __restrict__ Y, const float* __restrict__ SV) {
  __shared__ float lds[256 * 17];
  const int t = threadIdx.x;
  const size_t row = blockIdx.x;
  float* yr = Y + row * 4096;
  float v[16];
#pragma unroll
  for (int n2 = 0; n2 < 16; n2++) v[n2] = yr[n2 * 256 + t];
  fwht16(v);
  const int n1 = t >> 4, n0 = t & 15;
#pragma unroll
  for (int j2 = 0; j2 < 16; j2++) lds[(j2 * 16 + n1) * 17 + n0] = v[j2];
  __syncthreads();
#pragma unroll
  for (int k = 0; k < 16; k++) v[k] = lds[((t >> 4) * 16 + k) * 17 + (t & 15)];
  fwht16(v);
#pragma unroll
  for (int k = 0; k < 16; k++) lds[((t >> 4) * 16 + k) * 17 + (t & 15)] = v[k];
  __syncthreads();
#pragma unroll
  for (int k = 0; k < 16; k++) v[k] = lds[t * 17 + k];
  fwht16(v);
  // scale: (1/sqrt(4096)) * SCALE * SV[j] = 0.5 * SV[j]
  float outv[16];
#pragma unroll
  for (int k = 0; k < 16; k++) outv[k] = v[k] * 0.5f * SV[(size_t)t * 16 + k];
  float4* dst = (float4*)(yr + (size_t)t * 16);
#pragma unroll
  for (int k = 0; k < 4; k++)
    dst[k] = make_float4(outv[4 * k], outv[4 * k + 1], outv[4 * k + 2],
                         outv[4 * k + 3]);
}

extern "C" void kernel_launch(void* const* d_in, const int* in_sizes, int n_in,
                              void* d_out, int out_size, void* d_ws,
                              size_t ws_size, hipStream_t stream) {
  const float* x = (const float*)d_in[0];       // (B,S,N) f32
  const float* W = (const float*)d_in[1];       // (M,N) f32
  const float* SU = (const float*)d_in[2];      // (N,)
  const float* SV = (const float*)d_in[3];      // (M,)
  const float* Wscale = (const float*)d_in[4];  // (M,)
  const int N = in_sizes[2];                    // 4096
  const int M = in_sizes[3];                    // 4096
  const int T = in_sizes[0] / N;                // 16384 rows

  unsigned short* H1 = (unsigned short*)d_ws;           // T*N bf16 = 128 MB
  unsigned short* Wb = H1 + (size_t)T * N;              // M*N bf16 = 32 MB
  float* out = (float*)d_out;                           // T*M f32

  fwht1_kernel<<<T, 256, 0, stream>>>(x, SU, H1);
  const int total4 = (int)(((long)M * N) / 4);
  convw_kernel<<<(total4 + 255) / 256, 256, 0, stream>>>(
      (const float4*)W, Wscale, (uint2*)Wb, total4, N / 4);
  gemm_kernel<<<(T / 128) * (M / 128), 256, 0, stream>>>(H1, Wb, out, T, M, N);
  fwht2_kernel<<<T, 256, 0, stream>>>(out, SV);
}

// Round 2
// 758.363 us; speedup vs baseline: 1.3729x; 1.3729x over previous
//
#include <hip/hip_runtime.h>
#include <hip/hip_bf16.h>

typedef __bf16 bf16x8 __attribute__((ext_vector_type(8)));
typedef float f32x4 __attribute__((ext_vector_type(4)));

__device__ __forceinline__ void gload16(const void* g, void* l) {
  __builtin_amdgcn_global_load_lds(
      (const __attribute__((address_space(1))) void*)g,
      (__attribute__((address_space(3))) void*)l, 16, 0, 0);
}

__device__ __forceinline__ unsigned short f2bf(float f) {
  __hip_bfloat16 h = __float2bfloat16(f);
  union { __hip_bfloat16 h; unsigned short u; } c;
  c.h = h;
  return c.u;
}

__device__ __forceinline__ void fwht16(float v[16]) {
#pragma unroll
  for (int s = 1; s < 16; s <<= 1) {
#pragma unroll
    for (int i = 0; i < 16; i++) {
      if ((i & s) == 0) {
        float a = v[i], b = v[i | s];
        v[i] = a + b;
        v[i | s] = a - b;
      }
    }
  }
}

// ---------------- FWHT #1: h1 = bf16( fwht(x*SU) / 2048 ) ----------------
__global__ __launch_bounds__(256) void fwht1_kernel(
    const float* __restrict__ x, const float* __restrict__ SU,
    unsigned short* __restrict__ H1) {
  __shared__ float lds[256 * 17];
  const int t = threadIdx.x;
  const size_t row = blockIdx.x;
  const float* xr = x + row * 4096;
  float v[16];
#pragma unroll
  for (int n2 = 0; n2 < 16; n2++) {
    int n = n2 * 256 + t;
    v[n2] = xr[n] * SU[n];
  }
  fwht16(v);
  const int n1 = t >> 4, n0 = t & 15;
#pragma unroll
  for (int j2 = 0; j2 < 16; j2++) lds[(j2 * 16 + n1) * 17 + n0] = v[j2];
  __syncthreads();
#pragma unroll
  for (int k = 0; k < 16; k++) v[k] = lds[((t >> 4) * 16 + k) * 17 + (t & 15)];
  fwht16(v);
#pragma unroll
  for (int k = 0; k < 16; k++) lds[((t >> 4) * 16 + k) * 17 + (t & 15)] = v[k];
  __syncthreads();
#pragma unroll
  for (int k = 0; k < 16; k++) v[k] = lds[t * 17 + k];
  fwht16(v);
  const float cst = 1.0f / 2048.0f;
  union { unsigned short u[16]; uint4 q[2]; } o;
#pragma unroll
  for (int k = 0; k < 16; k++) o.u[k] = f2bf(v[k] * cst);
  uint4* dst = (uint4*)(H1 + row * 4096 + (size_t)t * 16);
  dst[0] = o.q[0];
  dst[1] = o.q[1];
}

// ---------------- W conversion: Wb[m][n] = bf16(W[m][n] * Wscale[m]) -------
__global__ __launch_bounds__(256) void convw_kernel(
    const float4* __restrict__ W4, const float* __restrict__ Wscale,
    uint2* __restrict__ Wb4, int total4, int Nq) {
  int i = blockIdx.x * 256 + threadIdx.x;
  if (i >= total4) return;
  float4 w = W4[i];
  float s = Wscale[i / Nq];
  unsigned int lo = (unsigned)f2bf(w.x * s) | ((unsigned)f2bf(w.y * s) << 16);
  unsigned int hi = (unsigned)f2bf(w.z * s) | ((unsigned)f2bf(w.w * s) << 16);
  Wb4[i] = make_uint2(lo, hi);
}

// ---------------- GEMM: 256x256 tile, BK=64, 8 waves, 8-phase schedule -----
// T2 LDS XOR-swizzle (chunk ^= row&7, 16B chunks), T3/T4 counted vmcnt(4)
// gates at phases 4/8 only, T5 setprio around MFMA clusters, T1 XCD swizzle.
// LDS: A,B each 2buf x 256rows x 64cols bf16 = 64KB -> 128KB total.

#define BARRIER()                          \
  do {                                     \
    asm volatile("" ::: "memory");         \
    __builtin_amdgcn_s_barrier();          \
    asm volatile("" ::: "memory");         \
  } while (0)
#define GATE4() asm volatile("s_waitcnt vmcnt(4)" ::: "memory")
#define GATE0() asm volatile("s_waitcnt vmcnt(0)" ::: "memory")

// stage one 128-row half-tile (128x64 bf16 = 16KB): 2 x gload16 per thread.
// LDS dest linear (wave-uniform base + lane*16); global source pre-swizzled
// so that ds_read applies chunk ^= (row&7) (both-sides involution).
__device__ __forceinline__ void stage_half(const unsigned short* __restrict__ g,
                                           unsigned short* l, int tid, int K) {
#pragma unroll
  for (int i = 0; i < 2; i++) {
    int idx = i * 512 + tid;
    int r = idx >> 3;
    int c = (idx & 7) ^ (r & 7);
    gload16(g + (size_t)r * K + c * 8, l + idx * 8);
  }
}

#define STAGE_A(d, hh, kt) \
  stage_half(Abase + (size_t)(hh) * 128 * K + (size_t)(kt) * 64, &As[d][(hh) * 8192], tid, K)
#define STAGE_B(d, hh, kt) \
  stage_half(Bbase + (size_t)(hh) * 128 * K + (size_t)(kt) * 64, &Bs[d][(hh) * 8192], tid, K)

#define LOAD_A(d, h)                                                          \
  {                                                                           \
    _Pragma("unroll") for (int i = 0; i < 4; i++) {                           \
      _Pragma("unroll") for (int ks = 0; ks < 2; ks++) {                      \
        int r = wm * 128 + (h) * 64 + i * 16 + fr;                            \
        int kc = ks * 4 + lhi;                                                \
        ah[i][ks] = *(const bf16x8*)&As[d][r * 64 + ((kc ^ (r & 7)) << 3)];   \
      }                                                                       \
    }                                                                         \
  }

#define LOAD_B(d, v, dst)                                                     \
  {                                                                           \
    _Pragma("unroll") for (int j = 0; j < 2; j++) {                           \
      _Pragma("unroll") for (int ks = 0; ks < 2; ks++) {                      \
        int r = wn * 64 + (v) * 32 + j * 16 + fr;                             \
        int kc = ks * 4 + lhi;                                                \
        dst[j][ks] = *(const bf16x8*)&Bs[d][r * 64 + ((kc ^ (r & 7)) << 3)];  \
      }                                                                       \
    }                                                                         \
  }

#define MFMA_PH(h, v, bvx)                                                    \
  {                                                                           \
    __builtin_amdgcn_s_setprio(1);                                            \
    _Pragma("unroll") for (int i = 0; i < 4; i++)                             \
      _Pragma("unroll") for (int j = 0; j < 2; j++)                           \
        _Pragma("unroll") for (int ks = 0; ks < 2; ks++)                      \
          acc[(h)*4 + i][(v)*2 + j] = __builtin_amdgcn_mfma_f32_16x16x32_bf16( \
              ah[i][ks], bvx[j][ks], acc[(h)*4 + i][(v)*2 + j], 0, 0, 0);     \
    __builtin_amdgcn_s_setprio(0);                                            \
  }

__global__ __launch_bounds__(512, 2) void gemm8_kernel(
    const unsigned short* __restrict__ A, const unsigned short* __restrict__ B,
    float* __restrict__ C, int M, int K, int NT) {
  __shared__ __align__(16) unsigned short As[2][256 * 64];
  __shared__ __align__(16) unsigned short Bs[2][256 * 64];
  const int nbn = M >> 8;
  const int cpx = gridDim.x >> 3;
  int bid = blockIdx.x;
  bid = (bid & 7) * cpx + (bid >> 3);  // XCD swizzle (grid % 8 == 0)
  const int brow = (bid / nbn) << 8;
  const int bcol = (bid % nbn) << 8;
  const int tid = threadIdx.x;
  const int lane = tid & 63;
  const int w = tid >> 6;          // 8 waves: 2 (M) x 4 (N)
  const int wm = w >> 2;           // 0..1 -> 128 rows each
  const int wn = w & 3;            // 0..3 -> 64 cols each
  const int fr = lane & 15;
  const int lhi = lane >> 4;

  const unsigned short* Abase = A + (size_t)brow * K;
  const unsigned short* Bbase = B + (size_t)bcol * K;

  f32x4 acc[8][4];
#pragma unroll
  for (int i = 0; i < 8; i++)
#pragma unroll
    for (int j = 0; j < 4; j++) acc[i][j] = (f32x4){0.f, 0.f, 0.f, 0.f};
  bf16x8 ah[4][2], bv0[2][2], bv1[2][2];

  // Prologue: tile0 (buf0) fully: B0,B1,A0,A1; tile1 (buf1): B0,B1.
  STAGE_B(0, 0, 0);
  STAGE_B(0, 1, 0);
  STAGE_A(0, 0, 0);
  STAGE_A(0, 1, 0);
  STAGE_B(1, 0, 1);
  STAGE_B(1, 1, 1);
  GATE4();  // wait tile0's 8 loads, leave tile1's 4 in flight
  BARRIER();

  for (int t = 0; t < NT / 2; ++t) {
    const bool last = (t == NT / 2 - 1);
    const int k1 = 2 * t + 1, k2 = 2 * t + 2, k3 = 2 * t + 3;
    // P1: read buf0 A-h0 + B-v0; stage buf1.A0 <- tile k1
    LOAD_A(0, 0);
    LOAD_B(0, 0, bv0);
    STAGE_A(1, 0, k1);
    BARRIER();
    MFMA_PH(0, 0, bv0);
    BARRIER();
    // P2: read buf0 B-v1; stage buf1.A1 <- k1
    LOAD_B(0, 1, bv1);
    STAGE_A(1, 1, k1);
    BARRIER();
    MFMA_PH(0, 1, bv1);
    BARRIER();
    // P3: read buf0 A-h1; stage buf0.B0 <- k2
    LOAD_A(0, 1);
    if (!last) STAGE_B(0, 0, k2);
    BARRIER();
    MFMA_PH(1, 1, bv1);
    BARRIER();
    // P4: stage buf0.B1 <- k2; GATE before crossing to buf1
    if (!last) STAGE_B(0, 1, k2);
    BARRIER();
    MFMA_PH(1, 0, bv0);
    if (!last) { GATE4(); } else { GATE0(); }
    BARRIER();
    // P5: read buf1 A-h0 + B-v0; stage buf0.A0 <- k2
    LOAD_A(1, 0);
    LOAD_B(1, 0, bv0);
    if (!last) STAGE_A(0, 0, k2);
    BARRIER();
    MFMA_PH(0, 0, bv0);
    BARRIER();
    // P6: read buf1 B-v1; stage buf0.A1 <- k2
    LOAD_B(1, 1, bv1);
    if (!last) STAGE_A(0, 1, k2);
    BARRIER();
    MFMA_PH(0, 1, bv1);
    BARRIER();
    // P7: read buf1 A-h1; stage buf1.B0 <- k3
    LOAD_A(1, 1);
    if (!last) STAGE_B(1, 0, k3);
    BARRIER();
    MFMA_PH(1, 1, bv1);
    BARRIER();
    // P8: stage buf1.B1 <- k3; GATE for next iter's buf0 reads
    if (!last) STAGE_B(1, 1, k3);
    BARRIER();
    MFMA_PH(1, 0, bv0);
    if (!last) GATE4();
    BARRIER();
  }

  // Epilogue: C/D layout col=lane&15, row=(lane>>4)*4+q  [m89-verified]
  const int crow0 = brow + wm * 128 + lhi * 4;
  const int ccol0 = bcol + wn * 64 + fr;
#pragma unroll
  for (int mi = 0; mi < 8; mi++)
#pragma unroll
    for (int nj = 0; nj < 4; nj++)
#pragma unroll
      for (int q = 0; q < 4; q++)
        C[(size_t)(crow0 + mi * 16 + q) * M + ccol0 + nj * 16] = acc[mi][nj][q];
}

// ---------------- FWHT #2 (in-place on d_out): out = fwht(Y)*0.5*SV ------
__global__ __launch_bounds__(256) void fwht2_kernel(
    float* __restrict__ Y, const float* __restrict__ SV) {
  __shared__ float lds[256 * 17];
  const int t = threadIdx.x;
  const size_t row = blockIdx.x;
  float* yr = Y + row * 4096;
  float v[16];
#pragma unroll
  for (int n2 = 0; n2 < 16; n2++) v[n2] = yr[n2 * 256 + t];
  fwht16(v);
  const int n1 = t >> 4, n0 = t & 15;
#pragma unroll
  for (int j2 = 0; j2 < 16; j2++) lds[(j2 * 16 + n1) * 17 + n0] = v[j2];
  __syncthreads();
#pragma unroll
  for (int k = 0; k < 16; k++) v[k] = lds[((t >> 4) * 16 + k) * 17 + (t & 15)];
  fwht16(v);
#pragma unroll
  for (int k = 0; k < 16; k++) lds[((t >> 4) * 16 + k) * 17 + (t & 15)] = v[k];
  __syncthreads();
#pragma unroll
  for (int k = 0; k < 16; k++) v[k] = lds[t * 17 + k];
  fwht16(v);
  float outv[16];
#pragma unroll
  for (int k = 0; k < 16; k++) outv[k] = v[k] * 0.5f * SV[(size_t)t * 16 + k];
  float4* dst = (float4*)(yr + (size_t)t * 16);
#pragma unroll
  for (int k = 0; k < 4; k++)
    dst[k] = make_float4(outv[4 * k], outv[4 * k + 1], outv[4 * k + 2],
                         outv[4 * k + 3]);
}

extern "C" void kernel_launch(void* const* d_in, const int* in_sizes, int n_in,
                              void* d_out, int out_size, void* d_ws,
                              size_t ws_size, hipStream_t stream) {
  const float* x = (const float*)d_in[0];
  const float* W = (const float*)d_in[1];
  const float* SU = (const float*)d_in[2];
  const float* SV = (const float*)d_in[3];
  const float* Wscale = (const float*)d_in[4];
  const int N = in_sizes[2];   // 4096
  const int M = in_sizes[3];   // 4096
  const int T = in_sizes[0] / N;  // 16384

  unsigned short* H1 = (unsigned short*)d_ws;
  unsigned short* Wb = H1 + (size_t)T * N;
  float* out = (float*)d_out;

  fwht1_kernel<<<T, 256, 0, stream>>>(x, SU, H1);
  const int total4 = (int)(((long)M * N) / 4);
  convw_kernel<<<(total4 + 255) / 256, 256, 0, stream>>>(
      (const float4*)W, Wscale, (uint2*)Wb, total4, N / 4);
  const int NT = N / 64;  // 64 K-tiles
  gemm8_kernel<<<(T / 256) * (M / 256), 512, 0, stream>>>(H1, Wb, out, M, N, NT);
  fwht2_kernel<<<T, 256, 0, stream>>>(out, SV);
}